// Round 1
// baseline (111.332 us; speedup 1.0000x reference)
//
#include <hip/hip_runtime.h>

typedef __bf16 bf16x8 __attribute__((ext_vector_type(8)));
typedef __bf16 bf16x4 __attribute__((ext_vector_type(4)));
typedef float f32x4 __attribute__((ext_vector_type(4)));

__global__ __launch_bounds__(256, 2)
void fattn(const float* __restrict__ qg, const float* __restrict__ kg,
           const float* __restrict__ vg, float* __restrict__ og) {
  constexpr int S = 2048, D = 64, QBLK = 128, KBLK = 32;
  constexpr float SC = 0.125f * 1.4426950408889634f;  // scale * log2(e)

  // XCD-aware swizzle: each XCD owns 4 contiguous-in-cache heads
  const int n = blockIdx.x;
  const int xcd = n & 7, idx = n >> 3;
  const int bh = 8 * (idx >> 4) + xcd;   // 0..31
  const int qt = idx & 15;               // q-tile 0..15

  const int tid = threadIdx.x;
  const int wave = tid >> 6, lane = tid & 63;
  const int lg = lane >> 4, lq = lane & 15;

  __shared__ __bf16 Ks[KBLK * 64];   // [32][64] bf16, 16B-column XOR swizzle
  __shared__ __bf16 Vt[64 * 36];     // [d=64][kv=32, pad to 36]

  const float* qp = qg + (size_t)bh * S * D;
  const float* kp = kg + (size_t)bh * S * D;
  const float* vp = vg + (size_t)bh * S * D;
  float*       op = og + (size_t)bh * S * D;

  const int base_q = qt * QBLK + wave * 32;

  // ---- Q fragments in registers: rows base_q..base_q+31, split 2 q-subtiles
  bf16x8 qf[2][2];
  for (int qs = 0; qs < 2; ++qs) {
    const float* qr = qp + (size_t)(base_q + 16 * qs + lq) * D + 8 * lg;
    for (int df = 0; df < 2; ++df) {
      float4 a = *(const float4*)(qr + 32 * df);
      float4 b = *(const float4*)(qr + 32 * df + 4);
      bf16x8 f;
      f[0] = (__bf16)a.x; f[1] = (__bf16)a.y; f[2] = (__bf16)a.z; f[3] = (__bf16)a.w;
      f[4] = (__bf16)b.x; f[5] = (__bf16)b.y; f[6] = (__bf16)b.z; f[7] = (__bf16)b.w;
      qf[qs][df] = f;
    }
  }

  f32x4 o[2][4] = {};
  float m_r[2] = {-1e30f, -1e30f};
  float ls[2] = {0.f, 0.f};

  const int ntiles = 4 * (qt + 1);
  for (int t = 0; t < ntiles; ++t) {
    const int kv0 = t * KBLK;
    __syncthreads();
    // ---- stage K (swizzled row-major) and V (transposed) fp32->bf16
    for (int rep = 0; rep < 2; ++rep) {
      int i = tid + rep * 256;
      int row = i >> 4, c4 = i & 15;
      const size_t goff = (size_t)(kv0 + row) * D + 4 * c4;
      float4 a = *(const float4*)(kp + goff);
      int c16s = (c4 >> 1) ^ (row & 7);
      bf16x4 w;
      w[0] = (__bf16)a.x; w[1] = (__bf16)a.y; w[2] = (__bf16)a.z; w[3] = (__bf16)a.w;
      *(bf16x4*)&Ks[row * 64 + c16s * 8 + (c4 & 1) * 4] = w;
      float4 b = *(const float4*)(vp + goff);
      int d0 = 4 * c4;
      Vt[(d0 + 0) * 36 + row] = (__bf16)b.x;
      Vt[(d0 + 1) * 36 + row] = (__bf16)b.y;
      Vt[(d0 + 2) * 36 + row] = (__bf16)b.z;
      Vt[(d0 + 3) * 36 + row] = (__bf16)b.w;
    }
    __syncthreads();

    // ---- K fragments (A-operand rows = kv), swizzled read: ~2-way free
    bf16x8 kf[2][2];
    for (int kt = 0; kt < 2; ++kt) {
      int r = kt * 16 + lq;
      for (int df = 0; df < 2; ++df) {
        int c16 = (4 * df + lg) ^ (r & 7);
        kf[kt][df] = *(const bf16x8*)&Ks[r * 64 + c16 * 8];
      }
    }
    // ---- V fragments (B-operand, true split-K layout from transposed tile)
    bf16x8 vf[4];
    for (int dt = 0; dt < 4; ++dt) {
      const __bf16* vr = &Vt[(16 * dt + lq) * 36];
      bf16x4 lo = *(const bf16x4*)&vr[4 * lg];
      bf16x4 hi = *(const bf16x4*)&vr[16 + 4 * lg];
      bf16x8 f;
      f[0] = lo[0]; f[1] = lo[1]; f[2] = lo[2]; f[3] = lo[3];
      f[4] = hi[0]; f[5] = hi[1]; f[6] = hi[2]; f[7] = hi[3];
      vf[dt] = f;
    }

    const bool maskT = (t >= 4 * qt);

    for (int qs = 0; qs < 2; ++qs) {
      // S^T tile: mfma(K, Q) -> lane holds S[q=lq][kv=16*kt+4*lg+reg]
      f32x4 st0 = {}, st1 = {};
      for (int df = 0; df < 2; ++df) {
        st0 = __builtin_amdgcn_mfma_f32_16x16x32_bf16(kf[0][df], qf[qs][df], st0, 0, 0, 0);
        st1 = __builtin_amdgcn_mfma_f32_16x16x32_bf16(kf[1][df], qf[qs][df], st1, 0, 0, 0);
      }
      float s[8];
      for (int r2 = 0; r2 < 4; ++r2) { s[r2] = st0[r2]; s[4 + r2] = st1[r2]; }
      if (maskT) {
        const int qabs = base_q + 16 * qs + lq;
        for (int kt = 0; kt < 2; ++kt)
          for (int r2 = 0; r2 < 4; ++r2) {
            int kvabs = kv0 + 16 * kt + 4 * lg + r2;
            if (kvabs > qabs) s[4 * kt + r2] = -1e30f;
          }
      }
      // wave-parallel online softmax (4 lanes per q-row: lg groups)
      float tmax = s[0];
      for (int i2 = 1; i2 < 8; ++i2) tmax = fmaxf(tmax, s[i2]);
      tmax = fmaxf(tmax, __shfl_xor(tmax, 16));
      tmax = fmaxf(tmax, __shfl_xor(tmax, 32));
      float mnew = fmaxf(m_r[qs], tmax);
      float fac = exp2f((m_r[qs] - mnew) * SC);
      m_r[qs] = mnew;
      float psum = 0.f;
      bf16x8 pa;
      for (int i2 = 0; i2 < 8; ++i2) {
        float p = exp2f((s[i2] - mnew) * SC);
        psum += p;
        pa[i2] = (__bf16)p;
      }
      psum += __shfl_xor(psum, 16);
      psum += __shfl_xor(psum, 32);
      ls[qs] = ls[qs] * fac + psum;
      // rescale O rows (O C-layout row = 4*lg+reg; fetch that row's factor)
      float facr[4];
      for (int r2 = 0; r2 < 4; ++r2) facr[r2] = __shfl(fac, (lg << 4) | (4 * lg + r2));
      for (int dt = 0; dt < 4; ++dt) {
        f32x4 acc = o[qs][dt];
        for (int r2 = 0; r2 < 4; ++r2) acc[r2] *= facr[r2];
        o[qs][dt] = __builtin_amdgcn_mfma_f32_16x16x32_bf16(pa, vf[dt], acc, 0, 0, 0);
      }
    }
  }

  // ---- epilogue: normalize by row-sum and store fp32
  for (int qs = 0; qs < 2; ++qs) {
    float inv = 1.0f / ls[qs];
    float invr[4];
    for (int r2 = 0; r2 < 4; ++r2) invr[r2] = __shfl(inv, (lg << 4) | (4 * lg + r2));
    for (int r2 = 0; r2 < 4; ++r2) {
      float* orow = op + (size_t)(base_q + 16 * qs + 4 * lg + r2) * D + lq;
      for (int dt = 0; dt < 4; ++dt)
        orow[16 * dt] = o[qs][dt][r2] * invr[r2];
    }
  }
}

extern "C" void kernel_launch(void* const* d_in, const int* in_sizes, int n_in,
                              void* d_out, int out_size, void* d_ws, size_t ws_size,
                              hipStream_t stream) {
  const float* q = (const float*)d_in[0];
  const float* k = (const float*)d_in[1];
  const float* v = (const float*)d_in[2];
  float* out = (float*)d_out;
  fattn<<<dim3(512), dim3(256), 0, stream>>>(q, k, v, out);
}

// Round 2
// 64.243 us; speedup vs baseline: 1.7330x; 1.7330x over previous
//
#include <hip/hip_runtime.h>

typedef __bf16 bf16x8 __attribute__((ext_vector_type(8)));
typedef __bf16 bf16x4 __attribute__((ext_vector_type(4)));
typedef float f32x4 __attribute__((ext_vector_type(4)));

constexpr int S = 2048, D = 64, KBLK = 64;
constexpr float SC = 0.125f * 1.4426950408889634f;  // scale * log2(e)

__global__ __launch_bounds__(256, 2)
void fattn(const float* __restrict__ qg, const float* __restrict__ kg,
           const float* __restrict__ vg, float* __restrict__ og) {
  const int bid = blockIdx.x;
  const int xcd = bid & 7, idx = bid >> 3;
  const int bh = 8 * (idx >> 4) + xcd;   // 4 heads per XCD chunk
  const int j  = idx & 15;               // pair index
  const int TA = j, TB = 31 - j;         // 64-row q-tiles, balanced pair
  const int NT = TB + 1;                 // kv-tiles needed (union)

  const int tid = threadIdx.x;
  const int wave = tid >> 6, lane = tid & 63;
  const int lg = lane >> 4, lq = lane & 15;

  __shared__ __bf16 Ks[2][64 * 64];   // [kv][d], 16B-col XOR swizzle
  __shared__ __bf16 Vt[2][64 * 68];   // [d][kv] transposed, pad 68

  const float* qp = qg + (size_t)bh * S * D;
  const float* kp = kg + (size_t)bh * S * D;
  const float* vp = vg + (size_t)bh * S * D;
  float*       op = og + (size_t)bh * S * D;

  const int qA = TA * 64 + wave * 16 + lq;
  const int qB = TB * 64 + wave * 16 + lq;

  // ---- Q fragments (rows = lane's lq), SC*log2e prefolded
  bf16x8 qfA[2], qfB[2];
#pragma unroll
  for (int df = 0; df < 2; ++df) {
    const float* qr = qp + (size_t)qA * D + 32 * df + 8 * lg;
    float4 a = *(const float4*)qr, b = *(const float4*)(qr + 4);
    bf16x8 f;
    f[0] = (__bf16)(a.x * SC); f[1] = (__bf16)(a.y * SC);
    f[2] = (__bf16)(a.z * SC); f[3] = (__bf16)(a.w * SC);
    f[4] = (__bf16)(b.x * SC); f[5] = (__bf16)(b.y * SC);
    f[6] = (__bf16)(b.z * SC); f[7] = (__bf16)(b.w * SC);
    qfA[df] = f;
    const float* qr2 = qp + (size_t)qB * D + 32 * df + 8 * lg;
    float4 c = *(const float4*)qr2, d = *(const float4*)(qr2 + 4);
    bf16x8 g;
    g[0] = (__bf16)(c.x * SC); g[1] = (__bf16)(c.y * SC);
    g[2] = (__bf16)(c.z * SC); g[3] = (__bf16)(c.w * SC);
    g[4] = (__bf16)(d.x * SC); g[5] = (__bf16)(d.y * SC);
    g[6] = (__bf16)(d.z * SC); g[7] = (__bf16)(d.w * SC);
    qfB[df] = g;
  }

  f32x4 oA[4] = {}, oB[4] = {};
  float mA = -1e30f, mB = -1e30f, lA = 0.f, lB = 0.f;

  float4 kr[4], vr[4];

  auto stage_load = [&](int t) {
#pragma unroll
    for (int rep = 0; rep < 4; ++rep) {
      int i2 = tid + 256 * rep;
      int row = i2 >> 4, c4 = i2 & 15;
      size_t g = (size_t)t * KBLK * D + (size_t)row * D + 4 * c4;
      kr[rep] = *(const float4*)(kp + g);
      vr[rep] = *(const float4*)(vp + g);
    }
  };
  auto stage_write = [&](int buf) {
#pragma unroll
    for (int rep = 0; rep < 4; ++rep) {
      int i2 = tid + 256 * rep;
      int row = i2 >> 4, c4 = i2 & 15;
      int c16s = (c4 >> 1) ^ (row & 7);
      bf16x4 w;
      w[0] = (__bf16)kr[rep].x; w[1] = (__bf16)kr[rep].y;
      w[2] = (__bf16)kr[rep].z; w[3] = (__bf16)kr[rep].w;
      *(bf16x4*)&Ks[buf][row * 64 + c16s * 8 + (c4 & 1) * 4] = w;
      int d0 = 4 * c4;
      Vt[buf][(d0 + 0) * 68 + row] = (__bf16)vr[rep].x;
      Vt[buf][(d0 + 1) * 68 + row] = (__bf16)vr[rep].y;
      Vt[buf][(d0 + 2) * 68 + row] = (__bf16)vr[rep].z;
      Vt[buf][(d0 + 3) * 68 + row] = (__bf16)vr[rep].w;
    }
  };

  bf16x8 kf[4][2], vf[2][4];

  auto compute_tile = [&](const bf16x8* qf, bool domask, int qabs, int kv0,
                          float& m, float& l, f32x4* o) {
    f32x4 st[4] = {};
#pragma unroll
    for (int kt = 0; kt < 4; ++kt) {
      st[kt] = __builtin_amdgcn_mfma_f32_16x16x32_bf16(kf[kt][0], qf[0], st[kt], 0, 0, 0);
      st[kt] = __builtin_amdgcn_mfma_f32_16x16x32_bf16(kf[kt][1], qf[1], st[kt], 0, 0, 0);
    }
    float s[16];
#pragma unroll
    for (int kt = 0; kt < 4; ++kt)
#pragma unroll
      for (int r = 0; r < 4; ++r) s[4 * kt + r] = st[kt][r];
    if (domask) {
#pragma unroll
      for (int kt = 0; kt < 4; ++kt)
#pragma unroll
        for (int r = 0; r < 4; ++r)
          if (kv0 + 16 * kt + 4 * lg + r > qabs) s[4 * kt + r] = -1e30f;
    }
    float tmax = s[0];
#pragma unroll
    for (int e = 1; e < 16; ++e) tmax = fmaxf(tmax, s[e]);
    tmax = fmaxf(tmax, __shfl_xor(tmax, 16));
    tmax = fmaxf(tmax, __shfl_xor(tmax, 32));
    float mnew = fmaxf(m, tmax);
    float fac = exp2f(m - mnew);
    m = mnew;
    float psum = 0.f;
    bf16x8 pa[2];
#pragma unroll
    for (int e = 0; e < 16; ++e) {
      float p = exp2f(s[e] - mnew);
      psum += p;
      pa[e >> 3][e & 7] = (__bf16)p;
    }
    psum += __shfl_xor(psum, 16);
    psum += __shfl_xor(psum, 32);
    l = l * fac + psum;
    float facr[4];
#pragma unroll
    for (int r = 0; r < 4; ++r) facr[r] = __shfl(fac, (lg << 4) | (4 * lg + r));
#pragma unroll
    for (int dt = 0; dt < 4; ++dt) {
      f32x4 acc = o[dt];
#pragma unroll
      for (int r = 0; r < 4; ++r) acc[r] *= facr[r];
      acc = __builtin_amdgcn_mfma_f32_16x16x32_bf16(pa[0], vf[0][dt], acc, 0, 0, 0);
      acc = __builtin_amdgcn_mfma_f32_16x16x32_bf16(pa[1], vf[1][dt], acc, 0, 0, 0);
      o[dt] = acc;
    }
  };

  // ---- prologue: stage tile 0
  stage_load(0);
  stage_write(0);
  __syncthreads();

  int cur = 0;
  for (int t = 0; t < NT; ++t) {
    const int kv0 = t * KBLK;
    const bool pf = (t + 1 < NT);
    if (pf) stage_load(t + 1);

    // ---- fragments from LDS[cur]
#pragma unroll
    for (int kt = 0; kt < 4; ++kt) {
      int r = kt * 16 + lq;
#pragma unroll
      for (int df = 0; df < 2; ++df) {
        int c16 = (4 * df + lg) ^ (r & 7);
        kf[kt][df] = *(const bf16x8*)&Ks[cur][r * 64 + c16 * 8];
      }
    }
#pragma unroll
    for (int ks = 0; ks < 2; ++ks)
#pragma unroll
      for (int dt = 0; dt < 4; ++dt) {
        const __bf16* vrow = &Vt[cur][(16 * dt + lq) * 68 + 32 * ks];
        bf16x4 lo = *(const bf16x4*)&vrow[4 * lg];
        bf16x4 hi = *(const bf16x4*)&vrow[16 + 4 * lg];
        bf16x8 f;
        f[0] = lo[0]; f[1] = lo[1]; f[2] = lo[2]; f[3] = lo[3];
        f[4] = hi[0]; f[5] = hi[1]; f[6] = hi[2]; f[7] = hi[3];
        vf[ks][dt] = f;
      }

    compute_tile(qfB, t == NT - 1, qB, kv0, mB, lB, oB);
    if (t <= TA) compute_tile(qfA, t == TA, qA, kv0, mA, lA, oA);

    if (pf) stage_write(cur ^ 1);
    __syncthreads();
    cur ^= 1;
  }

  // ---- epilogue
  auto store_tile = [&](int T, float l, const f32x4* o) {
    float inv = 1.0f / l;
    float invr[4];
#pragma unroll
    for (int r = 0; r < 4; ++r) invr[r] = __shfl(inv, (lg << 4) | (4 * lg + r));
#pragma unroll
    for (int r = 0; r < 4; ++r) {
      float* orow = op + (size_t)(T * 64 + wave * 16 + 4 * lg + r) * D + lq;
#pragma unroll
      for (int dt = 0; dt < 4; ++dt)
        orow[16 * dt] = o[dt][r] * invr[r];
    }
  };
  store_tile(TA, lA, oA);
  store_tile(TB, lB, oB);
}

extern "C" void kernel_launch(void* const* d_in, const int* in_sizes, int n_in,
                              void* d_out, int out_size, void* d_ws, size_t ws_size,
                              hipStream_t stream) {
  const float* q = (const float*)d_in[0];
  const float* k = (const float*)d_in[1];
  const float* v = (const float*)d_in[2];
  float* out = (float*)d_out;
  fattn<<<dim3(512), dim3(256), 0, stream>>>(q, k, v, out);
}

// Round 3
// 63.496 us; speedup vs baseline: 1.7534x; 1.0118x over previous
//
#include <hip/hip_runtime.h>

typedef __bf16 bf16x8 __attribute__((ext_vector_type(8)));
typedef __bf16 bf16x4 __attribute__((ext_vector_type(4)));
typedef float f32x4 __attribute__((ext_vector_type(4)));

constexpr int S = 2048, D = 64, KBLK = 64;
constexpr float SC = 0.125f * 1.4426950408889634f;  // scale * log2(e)
constexpr int NHEAD = 32, NTILE = S / KBLK;         // 32 kv-tiles per head
constexpr size_t TILE_ELE = (size_t)KBLK * D;       // 4096 bf16 = 8KB
constexpr size_t WS_HALF = (size_t)NHEAD * NTILE * TILE_ELE;

__device__ __forceinline__ void gll16(const __bf16* g, __bf16* l) {
  __builtin_amdgcn_global_load_lds(
      (const __attribute__((address_space(1))) void*)g,
      (__attribute__((address_space(3))) void*)l, 16, 0, 0);
}

// ---------- pre-pass: fp32 K/V -> bf16 swizzled tile images in ws ----------
__global__ __launch_bounds__(256, 4)
void prepass(const float* __restrict__ kg, const float* __restrict__ vg,
             __bf16* __restrict__ wsk, __bf16* __restrict__ wsv) {
  const int blk = blockIdx.x;            // head*32 + tile
  const int head = blk >> 5, tile = blk & 31;
  const int tid = threadIdx.x;
  const float* kp = kg + ((size_t)head * S + (size_t)tile * KBLK) * D;
  const float* vp = vg + ((size_t)head * S + (size_t)tile * KBLK) * D;
  __bf16* kt = wsk + (size_t)blk * TILE_ELE;
  __bf16* vt = wsv + (size_t)blk * TILE_ELE;

  __shared__ __bf16 Vl[KBLK * D];

#pragma unroll
  for (int rep = 0; rep < 4; ++rep) {
    int i = tid + 256 * rep;
    int row = i >> 4, c4 = i & 15;
    float4 a = *(const float4*)(kp + row * D + 4 * c4);
    bf16x4 w;
    w[0] = (__bf16)a.x; w[1] = (__bf16)a.y; w[2] = (__bf16)a.z; w[3] = (__bf16)a.w;
    int chunk = (c4 >> 1) ^ (row & 7);               // 16B-chunk XOR swizzle
    *(bf16x4*)&kt[row * 64 + chunk * 8 + (c4 & 1) * 4] = w;
    float4 b = *(const float4*)(vp + row * D + 4 * c4);
    bf16x4 u;
    u[0] = (__bf16)b.x; u[1] = (__bf16)b.y; u[2] = (__bf16)b.z; u[3] = (__bf16)b.w;
    *(bf16x4*)&Vl[row * 64 + 4 * c4] = u;
  }
  __syncthreads();
  // V^T image: elem offset = d*64 + cs*8 + e, cs = c ^ (d&7),
  // p = 8c+e encodes kv as [k5][k3][k2][k4][k1][k0]
#pragma unroll
  for (int rep = 0; rep < 2; ++rep) {
    int slot = tid + 256 * rep;          // 0..511
    int d = slot >> 3, cs = slot & 7;
    int c = cs ^ (d & 7);
    bf16x8 f;
#pragma unroll
    for (int e = 0; e < 8; ++e) {
      int p = 8 * c + e;
      int kv = 32 * (p >> 5) + 16 * ((p >> 2) & 1) + 8 * ((p >> 4) & 1)
             + 4 * ((p >> 3) & 1) + (p & 3);
      f[e] = Vl[kv * 64 + d];
    }
    *(bf16x8*)&vt[d * 64 + cs * 8] = f;
  }
}

// ---------------- main attention kernel (bf16 ws inputs) -------------------
__global__ __launch_bounds__(256, 2)
void fattn(const float* __restrict__ qg, const __bf16* __restrict__ wsk,
           const __bf16* __restrict__ wsv, float* __restrict__ og) {
  const int bid = blockIdx.x;
  const int xcd = bid & 7, idx = bid >> 3;
  const int bh = 8 * (idx >> 4) + xcd;
  const int j = idx & 15;
  const int TA = j, TB = 31 - j;         // balanced causal pair
  const int NT = TB + 1;

  const int tid = threadIdx.x;
  const int wave = tid >> 6, lane = tid & 63;
  const int lg = lane >> 4, lq = lane & 15;

  __shared__ __bf16 Ks[2][TILE_ELE];
  __shared__ __bf16 Vs[2][TILE_ELE];

  const float* qp = qg + (size_t)bh * S * D;
  float*       op = og + (size_t)bh * S * D;
  const __bf16* ktiles = wsk + (size_t)bh * NTILE * TILE_ELE;
  const __bf16* vtiles = wsv + (size_t)bh * NTILE * TILE_ELE;

  const int qA = TA * 64 + wave * 16 + lq;
  const int qB = TB * 64 + wave * 16 + lq;

  bf16x8 qfA[2], qfB[2];
#pragma unroll
  for (int df = 0; df < 2; ++df) {
    const float* qr = qp + (size_t)qA * D + 32 * df + 8 * lg;
    float4 a = *(const float4*)qr, b = *(const float4*)(qr + 4);
    bf16x8 f;
    f[0] = (__bf16)(a.x * SC); f[1] = (__bf16)(a.y * SC);
    f[2] = (__bf16)(a.z * SC); f[3] = (__bf16)(a.w * SC);
    f[4] = (__bf16)(b.x * SC); f[5] = (__bf16)(b.y * SC);
    f[6] = (__bf16)(b.z * SC); f[7] = (__bf16)(b.w * SC);
    qfA[df] = f;
    const float* qr2 = qp + (size_t)qB * D + 32 * df + 8 * lg;
    float4 c = *(const float4*)qr2, d = *(const float4*)(qr2 + 4);
    bf16x8 g;
    g[0] = (__bf16)(c.x * SC); g[1] = (__bf16)(c.y * SC);
    g[2] = (__bf16)(c.z * SC); g[3] = (__bf16)(c.w * SC);
    g[4] = (__bf16)(d.x * SC); g[5] = (__bf16)(d.y * SC);
    g[6] = (__bf16)(d.z * SC); g[7] = (__bf16)(d.w * SC);
    qfB[df] = g;
  }

  f32x4 oA[4] = {}, oB[4] = {};
  float mA = -1e30f, mB = -1e30f, lA = 0.f, lB = 0.f;

  auto stage = [&](int buf, int t) {
    const __bf16* kt = ktiles + (size_t)t * TILE_ELE;
    const __bf16* vt = vtiles + (size_t)t * TILE_ELE;
#pragma unroll
    for (int rep = 0; rep < 2; ++rep) {
      int ch = wave + 4 * rep;           // 0..7 1KB-chunks
      gll16(kt + ch * 512 + lane * 8, &Ks[buf][ch * 512]);
      gll16(vt + ch * 512 + lane * 8, &Vs[buf][ch * 512]);
    }
  };

  bf16x8 kf[4][2], vf[2][4];

  auto compute_tile = [&](const bf16x8* qf, bool domask, int qabs, int kv0,
                          float& m, float& l, f32x4* o) {
    f32x4 st[4] = {};
#pragma unroll
    for (int kt2 = 0; kt2 < 4; ++kt2) {
      st[kt2] = __builtin_amdgcn_mfma_f32_16x16x32_bf16(kf[kt2][0], qf[0], st[kt2], 0, 0, 0);
      st[kt2] = __builtin_amdgcn_mfma_f32_16x16x32_bf16(kf[kt2][1], qf[1], st[kt2], 0, 0, 0);
    }
    float s[16];
#pragma unroll
    for (int kt2 = 0; kt2 < 4; ++kt2)
#pragma unroll
      for (int r = 0; r < 4; ++r) s[4 * kt2 + r] = st[kt2][r];
    if (domask) {
#pragma unroll
      for (int kt2 = 0; kt2 < 4; ++kt2)
#pragma unroll
        for (int r = 0; r < 4; ++r)
          if (kv0 + 16 * kt2 + 4 * lg + r > qabs) s[4 * kt2 + r] = -1e30f;
    }
    float tmax = s[0];
#pragma unroll
    for (int e = 1; e < 16; ++e) tmax = fmaxf(tmax, s[e]);
    tmax = fmaxf(tmax, __shfl_xor(tmax, 16));
    tmax = fmaxf(tmax, __shfl_xor(tmax, 32));
    float mnew = fmaxf(m, tmax);
    float fac = exp2f(m - mnew);
    m = mnew;
    float psum = 0.f;
    bf16x8 pa[2];
#pragma unroll
    for (int e = 0; e < 16; ++e) {
      float p = exp2f(s[e] - mnew);
      psum += p;
      pa[e >> 3][e & 7] = (__bf16)p;
    }
    psum += __shfl_xor(psum, 16);
    psum += __shfl_xor(psum, 32);
    l = l * fac + psum;
    float facr[4];
#pragma unroll
    for (int r = 0; r < 4; ++r) facr[r] = __shfl(fac, (lg << 4) | (4 * lg + r));
#pragma unroll
    for (int dt = 0; dt < 4; ++dt) {
      f32x4 acc = o[dt];
#pragma unroll
      for (int r = 0; r < 4; ++r) acc[r] *= facr[r];
      acc = __builtin_amdgcn_mfma_f32_16x16x32_bf16(pa[0], vf[0][dt], acc, 0, 0, 0);
      acc = __builtin_amdgcn_mfma_f32_16x16x32_bf16(pa[1], vf[1][dt], acc, 0, 0, 0);
      o[dt] = acc;
    }
  };

  stage(0, 0);
  __syncthreads();

  int cur = 0;
  for (int t = 0; t < NT; ++t) {
    const int kv0 = t * KBLK;
    if (t + 1 < NT) stage(cur ^ 1, t + 1);

#pragma unroll
    for (int kt2 = 0; kt2 < 4; ++kt2) {
      int r = 16 * kt2 + lq;
#pragma unroll
      for (int df = 0; df < 2; ++df) {
        int c = (4 * df + lg) ^ (lq & 7);
        kf[kt2][df] = *(const bf16x8*)&Ks[cur][r * 64 + c * 8];
      }
    }
#pragma unroll
    for (int ks = 0; ks < 2; ++ks)
#pragma unroll
      for (int dt = 0; dt < 4; ++dt) {
        int c = (4 * ks + lg) ^ (lq & 7);
        vf[ks][dt] = *(const bf16x8*)&Vs[cur][(16 * dt + lq) * 64 + c * 8];
      }

    compute_tile(qfB, t == NT - 1, qB, kv0, mB, lB, oB);
    if (t <= TA) compute_tile(qfA, t == TA, qA, kv0, mA, lA, oA);

    __syncthreads();   // drains prefetch vmcnt + protects buffers
    cur ^= 1;
  }

  auto store_tile = [&](int T, float l, const f32x4* o) {
    float inv = 1.0f / l;
    float invr[4];
#pragma unroll
    for (int r = 0; r < 4; ++r) invr[r] = __shfl(inv, (lg << 4) | (4 * lg + r));
#pragma unroll
    for (int r = 0; r < 4; ++r) {
      float* orow = op + (size_t)(T * 64 + wave * 16 + 4 * lg + r) * D + lq;
#pragma unroll
      for (int dt = 0; dt < 4; ++dt)
        orow[16 * dt] = o[dt][r] * invr[r];
    }
  };
  store_tile(TA, lA, oA);
  store_tile(TB, lB, oB);
}

// ---------------- fallback (round-2 kernel) if ws too small ----------------
__global__ __launch_bounds__(256, 2)
void fattn_fb(const float* __restrict__ qg, const float* __restrict__ kg,
              const float* __restrict__ vg, float* __restrict__ og) {
  const int bid = blockIdx.x;
  const int xcd = bid & 7, idx = bid >> 3;
  const int bh = 8 * (idx >> 4) + xcd;
  const int j = idx & 15;
  const int TA = j, TB = 31 - j;
  const int NT = TB + 1;
  const int tid = threadIdx.x;
  const int wave = tid >> 6, lane = tid & 63;
  const int lg = lane >> 4, lq = lane & 15;
  __shared__ __bf16 Ks[2][64 * 64];
  __shared__ __bf16 Vt[2][64 * 68];
  const float* qp = qg + (size_t)bh * S * D;
  const float* kp = kg + (size_t)bh * S * D;
  const float* vp = vg + (size_t)bh * S * D;
  float*       op = og + (size_t)bh * S * D;
  const int qA = TA * 64 + wave * 16 + lq;
  const int qB = TB * 64 + wave * 16 + lq;
  bf16x8 qfA[2], qfB[2];
#pragma unroll
  for (int df = 0; df < 2; ++df) {
    const float* qr = qp + (size_t)qA * D + 32 * df + 8 * lg;
    float4 a = *(const float4*)qr, b = *(const float4*)(qr + 4);
    bf16x8 f;
    f[0] = (__bf16)(a.x * SC); f[1] = (__bf16)(a.y * SC);
    f[2] = (__bf16)(a.z * SC); f[3] = (__bf16)(a.w * SC);
    f[4] = (__bf16)(b.x * SC); f[5] = (__bf16)(b.y * SC);
    f[6] = (__bf16)(b.z * SC); f[7] = (__bf16)(b.w * SC);
    qfA[df] = f;
    const float* qr2 = qp + (size_t)qB * D + 32 * df + 8 * lg;
    float4 c = *(const float4*)qr2, d = *(const float4*)(qr2 + 4);
    bf16x8 g;
    g[0] = (__bf16)(c.x * SC); g[1] = (__bf16)(c.y * SC);
    g[2] = (__bf16)(c.z * SC); g[3] = (__bf16)(c.w * SC);
    g[4] = (__bf16)(d.x * SC); g[5] = (__bf16)(d.y * SC);
    g[6] = (__bf16)(d.z * SC); g[7] = (__bf16)(d.w * SC);
    qfB[df] = g;
  }
  f32x4 oA[4] = {}, oB[4] = {};
  float mA = -1e30f, mB = -1e30f, lA = 0.f, lB = 0.f;
  float4 kr[4], vr[4];
  auto stage_load = [&](int t) {
#pragma unroll
    for (int rep = 0; rep < 4; ++rep) {
      int i2 = tid + 256 * rep;
      int row = i2 >> 4, c4 = i2 & 15;
      size_t g = (size_t)t * KBLK * D + (size_t)row * D + 4 * c4;
      kr[rep] = *(const float4*)(kp + g);
      vr[rep] = *(const float4*)(vp + g);
    }
  };
  auto stage_write = [&](int buf) {
#pragma unroll
    for (int rep = 0; rep < 4; ++rep) {
      int i2 = tid + 256 * rep;
      int row = i2 >> 4, c4 = i2 & 15;
      int c16s = (c4 >> 1) ^ (row & 7);
      bf16x4 w;
      w[0] = (__bf16)kr[rep].x; w[1] = (__bf16)kr[rep].y;
      w[2] = (__bf16)kr[rep].z; w[3] = (__bf16)kr[rep].w;
      *(bf16x4*)&Ks[buf][row * 64 + c16s * 8 + (c4 & 1) * 4] = w;
      int d0 = 4 * c4;
      Vt[buf][(d0 + 0) * 68 + row] = (__bf16)vr[rep].x;
      Vt[buf][(d0 + 1) * 68 + row] = (__bf16)vr[rep].y;
      Vt[buf][(d0 + 2) * 68 + row] = (__bf16)vr[rep].z;
      Vt[buf][(d0 + 3) * 68 + row] = (__bf16)vr[rep].w;
    }
  };
  bf16x8 kf[4][2], vf[2][4];
  auto compute_tile = [&](const bf16x8* qf, bool domask, int qabs, int kv0,
                          float& m, float& l, f32x4* o) {
    f32x4 st[4] = {};
#pragma unroll
    for (int kt = 0; kt < 4; ++kt) {
      st[kt] = __builtin_amdgcn_mfma_f32_16x16x32_bf16(kf[kt][0], qf[0], st[kt], 0, 0, 0);
      st[kt] = __builtin_amdgcn_mfma_f32_16x16x32_bf16(kf[kt][1], qf[1], st[kt], 0, 0, 0);
    }
    float s[16];
#pragma unroll
    for (int kt = 0; kt < 4; ++kt)
#pragma unroll
      for (int r = 0; r < 4; ++r) s[4 * kt + r] = st[kt][r];
    if (domask) {
#pragma unroll
      for (int kt = 0; kt < 4; ++kt)
#pragma unroll
        for (int r = 0; r < 4; ++r)
          if (kv0 + 16 * kt + 4 * lg + r > qabs) s[4 * kt + r] = -1e30f;
    }
    float tmax = s[0];
#pragma unroll
    for (int e = 1; e < 16; ++e) tmax = fmaxf(tmax, s[e]);
    tmax = fmaxf(tmax, __shfl_xor(tmax, 16));
    tmax = fmaxf(tmax, __shfl_xor(tmax, 32));
    float mnew = fmaxf(m, tmax);
    float fac = exp2f(m - mnew);
    m = mnew;
    float psum = 0.f;
    bf16x8 pa[2];
#pragma unroll
    for (int e = 0; e < 16; ++e) {
      float p = exp2f(s[e] - mnew);
      psum += p;
      pa[e >> 3][e & 7] = (__bf16)p;
    }
    psum += __shfl_xor(psum, 16);
    psum += __shfl_xor(psum, 32);
    l = l * fac + psum;
    float facr[4];
#pragma unroll
    for (int r = 0; r < 4; ++r) facr[r] = __shfl(fac, (lg << 4) | (4 * lg + r));
#pragma unroll
    for (int dt = 0; dt < 4; ++dt) {
      f32x4 acc = o[dt];
#pragma unroll
      for (int r = 0; r < 4; ++r) acc[r] *= facr[r];
      acc = __builtin_amdgcn_mfma_f32_16x16x32_bf16(pa[0], vf[0][dt], acc, 0, 0, 0);
      acc = __builtin_amdgcn_mfma_f32_16x16x32_bf16(pa[1], vf[1][dt], acc, 0, 0, 0);
      o[dt] = acc;
    }
  };
  stage_load(0);
  stage_write(0);
  __syncthreads();
  int cur = 0;
  for (int t = 0; t < NT; ++t) {
    const int kv0 = t * KBLK;
    const bool pf = (t + 1 < NT);
    if (pf) stage_load(t + 1);
#pragma unroll
    for (int kt = 0; kt < 4; ++kt) {
      int r = kt * 16 + lq;
#pragma unroll
      for (int df = 0; df < 2; ++df) {
        int c16 = (4 * df + lg) ^ (r & 7);
        kf[kt][df] = *(const bf16x8*)&Ks[cur][r * 64 + c16 * 8];
      }
    }
#pragma unroll
    for (int ks = 0; ks < 2; ++ks)
#pragma unroll
      for (int dt = 0; dt < 4; ++dt) {
        const __bf16* vrow = &Vt[cur][(16 * dt + lq) * 68 + 32 * ks];
        bf16x4 lo = *(const bf16x4*)&vrow[4 * lg];
        bf16x4 hi = *(const bf16x4*)&vrow[16 + 4 * lg];
        bf16x8 f;
        f[0] = lo[0]; f[1] = lo[1]; f[2] = lo[2]; f[3] = lo[3];
        f[4] = hi[0]; f[5] = hi[1]; f[6] = hi[2]; f[7] = hi[3];
        vf[ks][dt] = f;
      }
    compute_tile(qfB, t == NT - 1, qB, kv0, mB, lB, oB);
    if (t <= TA) compute_tile(qfA, t == TA, qA, kv0, mA, lA, oA);
    if (pf) stage_write(cur ^ 1);
    __syncthreads();
    cur ^= 1;
  }
  auto store_tile = [&](int T, float l, const f32x4* o) {
    float inv = 1.0f / l;
    float invr[4];
#pragma unroll
    for (int r = 0; r < 4; ++r) invr[r] = __shfl(inv, (lg << 4) | (4 * lg + r));
#pragma unroll
    for (int r = 0; r < 4; ++r) {
      float* orow = op + (size_t)(T * 64 + wave * 16 + 4 * lg + r) * D + lq;
#pragma unroll
      for (int dt = 0; dt < 4; ++dt)
        orow[16 * dt] = o[dt][r] * invr[r];
    }
  };
  store_tile(TA, lA, oA);
  store_tile(TB, lB, oB);
}

extern "C" void kernel_launch(void* const* d_in, const int* in_sizes, int n_in,
                              void* d_out, int out_size, void* d_ws, size_t ws_size,
                              hipStream_t stream) {
  const float* q = (const float*)d_in[0];
  const float* k = (const float*)d_in[1];
  const float* v = (const float*)d_in[2];
  float* out = (float*)d_out;
  const size_t need = 2 * WS_HALF * sizeof(__bf16);  // 16 MB
  if (ws_size >= need) {
    __bf16* wsk = (__bf16*)d_ws;
    __bf16* wsv = wsk + WS_HALF;
    prepass<<<dim3(NHEAD * NTILE), dim3(256), 0, stream>>>(k, v, wsk, wsv);
    fattn<<<dim3(512), dim3(256), 0, stream>>>(q, wsk, wsv, out);
  } else {
    fattn_fb<<<dim3(512), dim3(256), 0, stream>>>(q, k, v, out);
  }
}